// Round 3
// baseline (5640.598 us; speedup 1.0000x reference)
//
#include <hip/hip_runtime.h>
#include <stdint.h>
#include <stdio.h>

// ---------------------------------------------------------------------------
// DilatedSparseRnnStack, round 7: timestep-skewed layers, ONE barrier/step.
// At step s each WG computes L0(t=s), L1(s-1), L2(s-2), L3(s-3), y(s-4).
// Every cross-WG dependency (outb, H-rings) is then exactly one step old ->
// single cluster-wide (per-wave-group) flag barrier per step; 259 barriers
// total vs 1024 phases in round 6. outb double-buffered by t&1 (WAR gap of
// 2 steps with a barrier between). Round-6 in-register cell kept verbatim.
// New: conflict-free tiled weight LDS (1KB contiguous per (kt,half) tile;
// round-6 strides were all ==4 mod 32 dwords -> 8-way conflicts = the 2.5e7
// counter), and lane-private C scratch ([slot][tid]*f32x4, coalesced).
// ---------------------------------------------------------------------------

typedef __attribute__((ext_vector_type(8))) short short8;
typedef __attribute__((ext_vector_type(4))) float f32x4;

#define DEVINL static __device__ __forceinline__

constexpr int TT = 256, BBATCH = 1024, INW = 64, HSW = 128, OSW = 128, NO = 8;
constexpr int ROWS = 128;                 // batch rows per cluster

constexpr int KLa[4]   = {192, 384, 448, 384};   // layer-0 dH folded: 320 -> 192
constexpr int DILa[4]  = {1, 3, 6, 12};
constexpr int PERa[4]  = {2, 4, 7, 13};   // h ring period = dil+1
// tiled weight layout: per (kt, half) a 1KB tile of 512 ushorts [lm][quad][8]
constexpr int WOFFa[4] = {0, 6144, 18432, 32768};   // ushort offsets
constexpr int WBYTES   = 90112;                     // 32 rows x 1408 k x 2B

constexpr int BIAS_B  = WBYTES;                    // 90,112
constexpr int WOUT_B  = BIAS_B + 512;              // 90,624
constexpr int WSTR    = 129;                       // wout pad
constexpr int BOUT_B  = WOUT_B + 8 * WSTR * 4;     // 94,752
constexpr int C3_B    = BOUT_B + 32;               // 94,784
constexpr int LDS_BYTES = C3_B + 12 * 256 * 16;    // 143,936 (<= 160 KiB)

// workspace layout (bytes)
//   [0,4096)     barrier flags: cluster c, wave w -> ws + c*512 + w*128, 32 words
//   [4096,4608)  per-XCD rank counters (c*64)
constexpr size_t WSBASE    = 8192;
constexpr size_t BH_OFF[4] = {0, 65536, 196608, 425984}; // h rings (P_l slots of 128x128 bf16)
constexpr size_t OUTB_OFF  = 851968;                     // 4 layers x 2 parity x 128x128 bf16
constexpr size_t CB_OFF    = OUTB_OFF + 8 * 32768;       // 1,114,112
constexpr size_t C1_SZ     = 32 * 3 * 256 * 16;          // 393,216
constexpr size_t C2_SZ     = 32 * 6 * 256 * 16;          // 786,432
constexpr size_t CLSZ      = CB_OFF + C1_SZ + C2_SZ;     // 2,293,760 (~2.2 MB)
constexpr size_t WS_NEED   = WSBASE + 8 * CLSZ;          // ~18.4 MB

__host__ __device__ constexpr int seg_type(int L, int k) {
  // 0 = x (fp32), 1 = prev-layer out, 2 = prevH, 3 = dH
  if (L == 0) return k < 64 ? 0 : 2;                    // dH folded into prevH
  if (L == 1) return k < 128 ? 1 : (k < 256 ? 2 : 3);
  if (L == 2) return k < 128 ? 1 : (k < 192 ? 0 : (k < 320 ? 2 : 3));
  return k < 128 ? 1 : (k < 256 ? 2 : 3);
}
__host__ __device__ constexpr int seg_start(int L, int k) {
  if (L == 0) return k < 64 ? 0 : 64;
  if (L == 1) return k < 128 ? 0 : (k < 256 ? 128 : 256);
  if (L == 2) return k < 128 ? 0 : (k < 192 ? 128 : (k < 320 ? 192 : 320));
  return k < 128 ? 0 : (k < 256 ? 128 : 256);
}

template <int N> struct IC { static constexpr int value = N; };

DEVINL unsigned short f2bf(float f) {        // RNE fp32 -> bf16
  union { float f; uint32_t u; } v; v.f = f;
  return (unsigned short)((v.u + 0x7FFFu + ((v.u >> 16) & 1u)) >> 16);
}
DEVINL float bf2f(unsigned short h) {
  union { uint32_t u; float f; } v; v.u = ((uint32_t)h) << 16;
  return v.f;
}
DEVINL float sigm(float x)  { return 1.0f / (1.0f + __expf(-x)); }
DEVINL float tanh_(float x) { return 1.0f - 2.0f / (__expf(2.0f * x) + 1.0f); }

DEVINL short8 zero_s8() { short8 v; for (int i = 0; i < 8; i++) v[i] = 0; return v; }
DEVINL f32x4  zero_f4() { f32x4  v; for (int i = 0; i < 4; i++) v[i] = 0.f; return v; }

DEVINL f32x4 mfma16(short8 a, short8 b, f32x4 c) {
  return __builtin_amdgcn_mfma_f32_16x16x32_bf16(a, b, c, 0, 0, 0);
}

DEVINL short8 ld8f(const float* p) {         // 8 fp32 -> bf16x8 fragment
  const f32x4 u0 = *(const f32x4*)p;
  const f32x4 u1 = *(const f32x4*)(p + 4);
  short8 r;
  r[0] = (short)f2bf(u0[0]); r[1] = (short)f2bf(u0[1]);
  r[2] = (short)f2bf(u0[2]); r[3] = (short)f2bf(u0[3]);
  r[4] = (short)f2bf(u1[0]); r[5] = (short)f2bf(u1[1]);
  r[6] = (short)f2bf(u1[2]); r[7] = (short)f2bf(u1[3]);
  return r;
}

__global__ void __launch_bounds__(256, 1)
rnn_stack_kernel(const float* __restrict__ x,
                 const float* __restrict__ W0, const float* __restrict__ b0,
                 const float* __restrict__ W1, const float* __restrict__ b1,
                 const float* __restrict__ W2, const float* __restrict__ b2,
                 const float* __restrict__ W3, const float* __restrict__ b3,
                 const float* __restrict__ Wout, const float* __restrict__ bout,
                 float* __restrict__ yout, char* __restrict__ ws)
{
  extern __shared__ char smem[];
  unsigned short* wlds = (unsigned short*)smem;
  float* biasl = (float*)(smem + BIAS_B);
  float* woutl = (float*)(smem + WOUT_B);
  float* boutl = (float*)(smem + BOUT_B);
  float* c3l   = (float*)(smem + C3_B);     // [(slot*256 + tid)*4] f32 (lane-private)

  const int tid = threadIdx.x;

  // ---- runtime cluster formation: c = physical XCD, g = rank on that XCD ----
  __shared__ unsigned s_cg;
  if (tid == 0) {
    unsigned xcc;
    asm volatile("s_getreg_b32 %0, hwreg(HW_REG_XCC_ID)" : "=s"(xcc));
    xcc &= 7u;
    unsigned rank = __hip_atomic_fetch_add(
        (unsigned*)(ws + 4096 + (size_t)xcc * 64), 1u,
        __ATOMIC_RELAXED, __HIP_MEMORY_SCOPE_AGENT);
    s_cg = (xcc << 8) | (rank & 31u);
  }
  __syncthreads();
  const int c = __builtin_amdgcn_readfirstlane((int)(s_cg >> 8));
  const int g = __builtin_amdgcn_readfirstlane((int)(s_cg & 255));

  char* cb = ws + WSBASE + (size_t)c * CLSZ;
  unsigned short* bufH[4];
  unsigned short* outb[8];                 // [layer*2 + t&1]
#pragma unroll
  for (int l = 0; l < 4; l++) {
    bufH[l] = (unsigned short*)(cb + BH_OFF[l]);
    outb[l * 2]     = (unsigned short*)(cb + OUTB_OFF + (size_t)(l * 2) * ROWS * OSW * 2);
    outb[l * 2 + 1] = (unsigned short*)(cb + OUTB_OFF + (size_t)(l * 2 + 1) * ROWS * OSW * 2);
  }
  float* bufC1 = (float*)(cb + CB_OFF + (size_t)g * (3 * 256 * 16));
  float* bufC2 = (float*)(cb + CB_OFF + C1_SZ + (size_t)g * (6 * 256 * 16));

  // ---- startup: weights -> tiled LDS (bf16); layer-0 dH block folded ----
  {
    const float* Wsrc[4] = {W0, W1, W2, W3};
    const float* bsrc[4] = {b0, b1, b2, b3};
    for (int l = 0; l < 4; l++) {
      const int K = KLa[l];
      const int Ksrc = (l == 0) ? 320 : K;             // W0 rows are length 320
      unsigned short* base = wlds + WOFFa[l];
      for (int n = 0; n < 32; n++) {
        const int grow = (n >> 3) * 256 + g * 8 + (n & 7);   // gate*SS + jglob
        const float* src = Wsrc[l] + (size_t)grow * Ksrc;
        for (int k = tid; k < K; k += 256) {
          float v = src[k];
          if (l == 0 && k >= 64) v += src[k + 128];    // fold W_dH into W_prevH
          // tile: [(kt*2 + half)*512 + lm*32 + quad*8 + e]
          base[((k >> 5) * 2 + (n >> 4)) * 512 + (n & 15) * 32 +
               ((k >> 3) & 3) * 8 + (k & 7)] = f2bf(v);
        }
      }
      if (tid < 32) biasl[l * 32 + tid] = bsrc[l][(tid >> 3) * 256 + g * 8 + (tid & 7)];
    }
    for (int i = tid; i < 8 * 128; i += 256) woutl[(i >> 7) * WSTR + (i & 127)] = Wout[i];
    if (tid < 8) boutl[tid] = bout[tid];
  }
  __syncthreads();           // the ONLY wg-wide sync; waves decouple after this

  const int wv = tid >> 6, lane = tid & 63, lm = lane & 15, quad = lane >> 4;
  const int m0 = wv * 32;          // wave's private 32 batch rows
  const bool hi = lm >= 8;
  const int j = lm & 7;            // this lane's j-column (0..7)
  const int mrow = m0 + (hi ? 16 : 0) + quad * 4;   // first of this lane's 4 rows

  // per-wave barrier flag block: 32 words (one per WG) for (cluster c, wave wv)
  unsigned* flg = (unsigned*)(ws + (size_t)c * 512 + (size_t)wv * 128);

  f32x4 pc[4];                     // prevC (4 rows x this lane's j), per layer
#pragma unroll
  for (int l = 0; l < 4; l++) pc[l] = zero_f4();

  auto arrive = [&](unsigned ep) {
    asm volatile("s_waitcnt vmcnt(0)" ::: "memory");   // publish stores in L2
    if (lane == 0)
      __hip_atomic_store(flg + g, ep, __ATOMIC_RELAXED, __HIP_MEMORY_SCOPE_AGENT);
  };
  auto waitbar = [&](unsigned ep) {
    asm volatile("" ::: "memory");
    for (;;) {
      unsigned v = __hip_atomic_load(flg + (lane & 31), __ATOMIC_RELAXED,
                                     __HIP_MEMORY_SCOPE_AGENT);
      if (__all((int)(v >= ep))) break;
      __builtin_amdgcn_s_sleep(1);
    }
    asm volatile("buffer_inv sc0" ::: "memory");   // L1 invalidate (XCD acquire)
  };

  // ---- one full layer: gates MFMA + in-register cell + publish ----
  auto do_layer = [&](auto Lc, int t) {
    constexpr int L = decltype(Lc)::value;
    constexpr int K = KLa[L];
    constexpr int NKT = K / 32;
    constexpr int DL = DILa[L];
    constexpr int P = PERa[L];
    if (t < 0 || t >= TT) return;
    const unsigned short* wl = wlds + WOFFa[L];
    const float bb0 = biasl[L * 32 + lm] + (lm < 8 ? 1.0f : 0.0f);  // fg bias +1
    const float bb1 = biasl[L * 32 + 16 + lm];
    f32x4 acc00 = (f32x4){bb0, bb0, bb0, bb0};
    f32x4 acc10 = acc00;
    f32x4 acc01 = (f32x4){bb1, bb1, bb1, bb1};
    f32x4 acc11 = acc01;
    const unsigned short* phb =
        (t >= 1) ? bufH[L] + (size_t)((t - 1) % P) * ROWS * HSW : nullptr;
    const unsigned short* dhb =
        (t >= DL) ? bufH[L] + (size_t)((t - DL) % P) * ROWS * HSW : phb;
    const unsigned short* ob = (L > 0) ? outb[(L - 1) * 2 + (t & 1)] : nullptr;
    const float* xb = x + ((size_t)t * BBATCH + (size_t)c * ROWS) * INW;

    // hoisted dC load (lane-private scratch; off the cell critical path)
    f32x4 dC = zero_f4();
    if constexpr (L == 1) { if (t >= DL) dC = *(const f32x4*)(bufC1 + ((size_t)(t % 3) * 256 + tid) * 4); }
    if constexpr (L == 2) { if (t >= DL) dC = *(const f32x4*)(bufC2 + ((size_t)(t % 6) * 256 + tid) * 4); }
    if constexpr (L == 3) { if (t >= DL) dC = *(const f32x4*)(c3l + ((size_t)(t % 12) * 256 + tid) * 4); }

#pragma unroll
    for (int kt = 0; kt < NKT; kt++) {
      const int sty = seg_type(L, kt * 32);
      const int sst = seg_start(L, kt * 32);
      const int kloc = kt * 32 - sst + quad * 8;
      short8 a0, a1;
      if (sty == 0) {
        const float* p = xb + (size_t)(m0 + lm) * INW + kloc;
        a0 = ld8f(p);
        a1 = ld8f(p + 16 * INW);
      } else if (sty == 1) {
        const unsigned short* p = ob + (size_t)(m0 + lm) * HSW + kloc;
        a0 = *(const short8*)p;
        a1 = *(const short8*)(p + 16 * HSW);
      } else {
        const unsigned short* sb = (sty == 2) ? phb : dhb;
        if (sb) {
          const unsigned short* p = sb + (size_t)(m0 + lm) * HSW + kloc;
          a0 = *(const short8*)p;
          a1 = *(const short8*)(p + 16 * HSW);
        } else {
          a0 = zero_s8();
          a1 = zero_s8();
        }
      }
      // tiled, conflict-free weight reads: contiguous 1KB per (kt,half)
      const short8 bf0 = *(const short8*)(wl + (kt * 2 + 0) * 512 + lm * 32 + quad * 8);
      const short8 bf1 = *(const short8*)(wl + (kt * 2 + 1) * 512 + lm * 32 + quad * 8);
      acc00 = mfma16(a0, bf0, acc00);
      acc01 = mfma16(a0, bf1, acc01);
      acc10 = mfma16(a1, bf0, acc10);
      acc11 = mfma16(a1, bf1, acc11);
    }
    // gate exchange: lanes lm and lm^8 hold complementary gate columns
    f32x4 s00, s01, s10, s11;
#pragma unroll
    for (int r = 0; r < 4; r++) {
      s00[r] = __shfl_xor(acc00[r], 8);
      s01[r] = __shfl_xor(acc01[r], 8);
      s10[r] = __shfl_xor(acc10[r], 8);
      s11[r] = __shfl_xor(acc11[r], 8);
    }
    f32x4 G0, G1, G2, G3;
#pragma unroll
    for (int r = 0; r < 4; r++) {
      G0[r] = hi ? s10[r] : acc00[r];
      G1[r] = hi ? acc10[r] : s00[r];
      G2[r] = hi ? s11[r] : acc01[r];
      G3[r] = hi ? acc11[r] : s01[r];
    }
    const f32x4 pcv = pc[L];
    f32x4 nC, wh;
#pragma unroll
    for (int q = 0; q < 4; q++) {
      const float fg = sigm(G0[q]);        // bias & +1.0 already in acc init
      const float cd = tanh_(G1[q]);
      const float og = sigm(G3[q]);
      float wc;
      if constexpr (L == 0) {
        wc = pcv[q];                       // dil=1: alpha*prevC+(1-alpha)*prevC
      } else {
        const float al = sigm(G2[q]);
        wc = (t >= DL) ? (al * pcv[q] + (1.0f - al) * dC[q]) : pcv[q];
      }
      const float nc = (t >= 1) ? (fg * wc + (1.0f - fg) * cd) : cd;
      nC[q] = nc;
      wh[q] = og * nc;
    }
    if constexpr (L == 1) *(f32x4*)(bufC1 + ((size_t)(t % 3) * 256 + tid) * 4) = nC;
    if constexpr (L == 2) *(f32x4*)(bufC2 + ((size_t)(t % 6) * 256 + tid) * 4) = nC;
    if constexpr (L == 3) *(f32x4*)(c3l + ((size_t)(t % 12) * 256 + tid) * 4) = nC;
    pc[L] = nC;
    const int jg = g * 8 + j;
    unsigned short* outw = outb[L * 2 + (t & 1)];
#pragma unroll
    for (int r = 0; r < 4; r++) {
      const unsigned short us = f2bf(wh[r]);
      const int row = mrow + r;
      if (g < 16) outw[(size_t)row * OSW + jg] = us;
      else bufH[L][((size_t)(t % P) * ROWS + row) * HSW + (jg - 128)] = us;
    }
  };

  // ---- epilogue: wave computes y for its private row r = m0 + g ----
  auto epilogue = [&](int tt) {
    const int r = m0 + g;
    const unsigned short* orow = outb[3 * 2 + (tt & 1)] + (size_t)r * OSW;
    const int o = lane >> 3, s = lane & 7;
    const short8 v0 = *(const short8*)(orow + s * 16);
    const short8 v1 = *(const short8*)(orow + s * 16 + 8);
    float part = 0.f;
#pragma unroll
    for (int i = 0; i < 8; i++)
      part += bf2f((unsigned short)v0[i]) * woutl[o * WSTR + s * 16 + i];
#pragma unroll
    for (int i = 0; i < 8; i++)
      part += bf2f((unsigned short)v1[i]) * woutl[o * WSTR + s * 16 + 8 + i];
    part += __shfl_down(part, 4);
    part += __shfl_down(part, 2);
    part += __shfl_down(part, 1);
    if (s == 0)
      yout[((size_t)tt * BBATCH + (size_t)c * ROWS + r) * NO + o] = part + boutl[o];
  };

  // ---- main loop: skewed layers, ONE barrier per step ----
  for (int s = 0; s < TT + 3; s++) {
    do_layer(IC<0>{}, s);
    do_layer(IC<1>{}, s - 1);
    do_layer(IC<2>{}, s - 2);
    do_layer(IC<3>{}, s - 3);
    if (s >= 4) epilogue(s - 4);
    arrive((unsigned)(s + 1));
    waitbar((unsigned)(s + 1));
  }
  epilogue(TT - 1);
}

extern "C" void kernel_launch(void* const* d_in, const int* in_sizes, int n_in,
                              void* d_out, int out_size, void* d_ws, size_t ws_size,
                              hipStream_t stream) {
  const float* x    = (const float*)d_in[0];
  const float* W0   = (const float*)d_in[1];
  const float* b0   = (const float*)d_in[2];
  const float* W1   = (const float*)d_in[3];
  const float* b1   = (const float*)d_in[4];
  const float* W2   = (const float*)d_in[5];
  const float* b2   = (const float*)d_in[6];
  const float* W3   = (const float*)d_in[7];
  const float* b3   = (const float*)d_in[8];
  const float* Wout = (const float*)d_in[9];
  const float* bout = (const float*)d_in[10];
  float* out = (float*)d_out;
  char* ws = (char*)d_ws;

  if (ws_size < WS_NEED) {
    fprintf(stderr, "kernel_launch: ws_size %zu < needed %zu\n", ws_size, (size_t)WS_NEED);
    return;
  }

  // zero barrier flags + rank counters (ws is poisoned 0xAA before every launch)
  hipMemsetAsync(d_ws, 0, 8192, stream);

  hipError_t e = hipFuncSetAttribute((const void*)rnn_stack_kernel,
                                     hipFuncAttributeMaxDynamicSharedMemorySize,
                                     LDS_BYTES);
  if (e != hipSuccess) fprintf(stderr, "hipFuncSetAttribute: %d\n", (int)e);

  rnn_stack_kernel<<<dim3(256), dim3(256), LDS_BYTES, stream>>>(
      x, W0, b0, W1, b1, W2, b2, W3, b3, Wout, bout, out, ws);
  e = hipGetLastError();
  if (e != hipSuccess) fprintf(stderr, "launch error: %d\n", (int)e);
}